// Round 7
// baseline (28.632 us; speedup 1.0000x reference)
//
#include <hip/hip_runtime.h>

// Problem constants (match reference setup_inputs)
#define BB 4
#define HH 1024
#define WW 1024
#define NC 12
#define GD 16
#define GH 16
#define GW 8

// LDS slab H[row][x][z][c]: one dword = half2( F(x,z,c), F(x,z+1,c) )
// (z-duplicated f16, y already lerped). z-stride 12 dwords, x-stride 196.
#define ZSD 12
#define XSD 196
#define HSZ (GW * XSD)   // 1568 dwords = 6272 B per row slab

typedef _Float16 h2 __attribute__((ext_vector_type(2)));
typedef float f4 __attribute__((ext_vector_type(4)));   // ext-vector for nt builtins
union HU { uint u; h2 h; };

// x-lerp both z corners in packed f16, then z-lerp in f32.
#define CH(ua_, ub_, dst_) do {                                   \
    HU A_, B_; A_.u = (ua_); B_.u = (ub_);                        \
    h2 m_ = A_.h + wx2 * (B_.h - A_.h);                           \
    float m0_ = (float)m_.x;                                      \
    float m1_ = (float)m_.y;                                      \
    dst_ = fmaf(wz, m1_ - m0_, m0_);                              \
} while (0)

__device__ __forceinline__ f4 ntld(const float* p) {
    return __builtin_nontemporal_load((const f4*)p);
}

__device__ __forceinline__ void run4(const uint* __restrict__ Hs,
                                     const f4& r4, const f4& g4, const f4& b4,
                                     float* __restrict__ outp, int tid,
                                     size_t plane)
{
    f4 o0, o1, o2;

#pragma unroll
    for (int p = 0; p < 4; p++) {
        const int px = 4 * tid + p;
        const float r = r4[p], g = g4[p], bl = b4[p];

        float ux = fminf(px * (7.0f / 1023.0f), 7.0f);
        int x0 = (int)ux;
        int x1 = min(x0 + 1, GW - 1);
        float wx = ux - (float)x0;
        _Float16 wxh = (_Float16)wx;
        h2 wx2 = h2{wxh, wxh};

        float lum = 0.299f * r + 0.587f * g + 0.114f * bl;
        float uz = fminf(fmaxf(lum * 15.0f, 0.0f), 15.0f);
        int z0 = (int)uz;
        float wz = uz - (float)z0;

        const uint* pa = Hs + x0 * XSD + z0 * ZSD;
        const uint* pb = Hs + x1 * XSD + z0 * ZSD;
        const uint4 qa0 = ((const uint4*)pa)[0];
        const uint4 qa1 = ((const uint4*)pa)[1];
        const uint4 qa2 = ((const uint4*)pa)[2];
        const uint4 qb0 = ((const uint4*)pb)[0];
        const uint4 qb1 = ((const uint4*)pb)[1];
        const uint4 qb2 = ((const uint4*)pb)[2];

        float c0, c1, c2, c3, c4, c5, c6, c7, c8, c9, c10, c11;
        CH(qa0.x, qb0.x, c0);  CH(qa0.y, qb0.y, c1);
        CH(qa0.z, qb0.z, c2);  CH(qa0.w, qb0.w, c3);
        CH(qa1.x, qb1.x, c4);  CH(qa1.y, qb1.y, c5);
        CH(qa1.z, qb1.z, c6);  CH(qa1.w, qb1.w, c7);
        CH(qa2.x, qb2.x, c8);  CH(qa2.y, qb2.y, c9);
        CH(qa2.z, qb2.z, c10); CH(qa2.w, qb2.w, c11);

        float v0 = c0 * r + c1 * g + c2  * bl + c9;
        float v1 = c3 * r + c4 * g + c5  * bl + c10;
        float v2 = c6 * r + c7 * g + c8  * bl + c11;
        o0[p] = fminf(fmaxf(v0, 0.0f), 1.0f);
        o1[p] = fminf(fmaxf(v1, 0.0f), 1.0f);
        o2[p] = fminf(fmaxf(v2, 0.0f), 1.0f);
    }

    __builtin_nontemporal_store(o0, (f4*)(outp + 4 * tid));
    __builtin_nontemporal_store(o1, (f4*)(outp + 4 * tid + plane));
    __builtin_nontemporal_store(o2, (f4*)(outp + 4 * tid + 2 * plane));
}

__global__ __launch_bounds__(256) void bgrid_row4(const float* __restrict__ img,
                                                  const float* __restrict__ grid,
                                                  float* __restrict__ out)
{
    const int yb = blockIdx.x * 4;          // rows yb..yb+3
    const int b = blockIdx.y;
    const int tid = threadIdx.x;

    __shared__ __align__(16) uint H[4][HSZ];   // 25 KB

    const size_t plane = (size_t)HH * WW;
    const size_t rbase = (size_t)b * 3 * plane + (size_t)yb * WW;
    const float* ip = img + rbase + 4 * tid;

    // ---- prefetch rows 0,1 at entry (in flight during staging) ----
    const f4 rA = ntld(ip);
    const f4 gA = ntld(ip + plane);
    const f4 bA = ntld(ip + 2 * plane);
    const f4 rB = ntld(ip + WW);
    const f4 gB = ntld(ip + WW + plane);
    const f4 bB = ntld(ip + WW + 2 * plane);

    // ---- per-row y constants (block-uniform scalars) ----
    float uyv[4]; int y0v[4]; int y1v[4];
#pragma unroll
    for (int r = 0; r < 4; r++) {
        float uy = fminf((yb + r) * (15.0f / 1023.0f), 15.0f);
        uyv[r] = uy;
        y0v[r] = (int)uy;
        y1v[r] = min(y0v[r] + 1, GH - 1);
    }
    const bool same_cell = (y0v[0] == y0v[3]);

    // ---- stage y-lerped, z-dup'd f16 slabs for 4 rows ----
    const float* gbase = grid + (size_t)b * (NC * GD * GH * GW); // [c][z][y][x]
#pragma unroll
    for (int j = 0; j < 6; j++) {
        int t = tid + 256 * j;          // 0..1535 = 8x * 16z * 12c
        int x = t & 7;
        int z = (t >> 3) & 15;
        int c = t >> 7;
        int zp = min(z + 1, GD - 1);
        const float* bc = gbase + c * (GD * GH * GW) + x;
        int off = x * XSD + z * ZSD + c;
        if (same_cell) {
            const int ya0 = y0v[0], ya1 = y1v[0];
            float a0 = bc[(z  * GH + ya0) * GW];
            float a1 = bc[(z  * GH + ya1) * GW];
            float e0 = bc[(zp * GH + ya0) * GW];
            float e1 = bc[(zp * GH + ya1) * GW];
            float d0 = a1 - a0, d1 = e1 - e0;
#pragma unroll
            for (int r = 0; r < 4; r++) {
                float w = uyv[r] - (float)ya0;
                HU pk;
                pk.h = h2{(_Float16)fmaf(w, d0, a0), (_Float16)fmaf(w, d1, e0)};
                H[r][off] = pk.u;
            }
        } else {
#pragma unroll
            for (int r = 0; r < 4; r++) {
                const int yy0 = y0v[r], yy1 = y1v[r];
                float a0 = bc[(z  * GH + yy0) * GW];
                float a1 = bc[(z  * GH + yy1) * GW];
                float e0 = bc[(zp * GH + yy0) * GW];
                float e1 = bc[(zp * GH + yy1) * GW];
                float w = uyv[r] - (float)yy0;
                HU pk;
                pk.h = h2{(_Float16)fmaf(w, a1 - a0, a0), (_Float16)fmaf(w, e1 - e0, e0)};
                H[r][off] = pk.u;
            }
        }
    }

    // ---- prefetch rows 2,3 (latency covered by rows 0-1 compute) ----
    const f4 rC = ntld(ip + 2 * WW);
    const f4 gC = ntld(ip + 2 * WW + plane);
    const f4 bC = ntld(ip + 2 * WW + 2 * plane);
    const f4 rD = ntld(ip + 3 * WW);
    const f4 gD = ntld(ip + 3 * WW + plane);
    const f4 bD = ntld(ip + 3 * WW + 2 * plane);

    __syncthreads();

    run4(H[0], rA, gA, bA, out + rbase,          tid, plane);
    run4(H[1], rB, gB, bB, out + rbase + WW,     tid, plane);
    run4(H[2], rC, gC, bC, out + rbase + 2 * WW, tid, plane);
    run4(H[3], rD, gD, bD, out + rbase + 3 * WW, tid, plane);
}

extern "C" void kernel_launch(void* const* d_in, const int* in_sizes, int n_in,
                              void* d_out, int out_size, void* d_ws, size_t ws_size,
                              hipStream_t stream) {
    const float* grid  = (const float*)d_in[0];
    const float* image = (const float*)d_in[1];
    float* out = (float*)d_out;

    dim3 blk(256);
    dim3 grd(HH / 4, BB);   // one block per (4 rows, batch)
    bgrid_row4<<<grd, blk, 0, stream>>>(image, grid, out);
}

// Round 8
// 27.134 us; speedup vs baseline: 1.0552x; 1.0552x over previous
//
#include <hip/hip_runtime.h>

// Problem constants (match reference setup_inputs)
#define BB 4
#define HH 1024
#define WW 1024
#define NC 12
#define GD 16
#define GH 16
#define GW 8

// LDS slab H[row][x][z][c]: one dword = half2( F(x,z,c), F(x,z+1,c) )
// (z-duplicated f16, y already lerped). z-stride 12 dwords, x-stride 196.
#define ZSD 12
#define XSD 196
#define HSZ (GW * XSD)   // 1568 dwords = 6272 B per row slab

typedef _Float16 h2 __attribute__((ext_vector_type(2)));
typedef float f4 __attribute__((ext_vector_type(4)));
union HU { uint u; h2 h; };

// x-lerp both z corners in packed f16, then z-lerp in f32.
#define CH(ua_, ub_, dst_) do {                                   \
    HU A_, B_; A_.u = (ua_); B_.u = (ub_);                        \
    h2 m_ = A_.h + wx2 * (B_.h - A_.h);                           \
    float m0_ = (float)m_.x;                                      \
    float m1_ = (float)m_.y;                                      \
    dst_ = fmaf(wz, m1_ - m0_, m0_);                              \
} while (0)

__device__ __forceinline__ f4 ld4(const float* p) {
    return *(const f4*)p;
}

__device__ __forceinline__ void run4(const uint* __restrict__ Hs,
                                     const f4& r4, const f4& g4, const f4& b4,
                                     float* __restrict__ outp, int tid,
                                     size_t plane)
{
    f4 o0, o1, o2;

#pragma unroll
    for (int p = 0; p < 4; p++) {
        const int px = 4 * tid + p;
        const float r = r4[p], g = g4[p], bl = b4[p];

        float ux = fminf(px * (7.0f / 1023.0f), 7.0f);
        int x0 = (int)ux;
        int x1 = min(x0 + 1, GW - 1);
        float wx = ux - (float)x0;
        _Float16 wxh = (_Float16)wx;
        h2 wx2 = h2{wxh, wxh};

        float lum = 0.299f * r + 0.587f * g + 0.114f * bl;
        float uz = fminf(fmaxf(lum * 15.0f, 0.0f), 15.0f);
        int z0 = (int)uz;
        float wz = uz - (float)z0;

        const uint* pa = Hs + x0 * XSD + z0 * ZSD;
        const uint* pb = Hs + x1 * XSD + z0 * ZSD;
        const uint4 qa0 = ((const uint4*)pa)[0];
        const uint4 qa1 = ((const uint4*)pa)[1];
        const uint4 qa2 = ((const uint4*)pa)[2];
        const uint4 qb0 = ((const uint4*)pb)[0];
        const uint4 qb1 = ((const uint4*)pb)[1];
        const uint4 qb2 = ((const uint4*)pb)[2];

        float c0, c1, c2, c3, c4, c5, c6, c7, c8, c9, c10, c11;
        CH(qa0.x, qb0.x, c0);  CH(qa0.y, qb0.y, c1);
        CH(qa0.z, qb0.z, c2);  CH(qa0.w, qb0.w, c3);
        CH(qa1.x, qb1.x, c4);  CH(qa1.y, qb1.y, c5);
        CH(qa1.z, qb1.z, c6);  CH(qa1.w, qb1.w, c7);
        CH(qa2.x, qb2.x, c8);  CH(qa2.y, qb2.y, c9);
        CH(qa2.z, qb2.z, c10); CH(qa2.w, qb2.w, c11);

        float v0 = c0 * r + c1 * g + c2  * bl + c9;
        float v1 = c3 * r + c4 * g + c5  * bl + c10;
        float v2 = c6 * r + c7 * g + c8  * bl + c11;
        o0[p] = fminf(fmaxf(v0, 0.0f), 1.0f);
        o1[p] = fminf(fmaxf(v1, 0.0f), 1.0f);
        o2[p] = fminf(fmaxf(v2, 0.0f), 1.0f);
    }

    *(f4*)(outp + 4 * tid) = o0;
    *(f4*)(outp + 4 * tid + plane) = o1;
    *(f4*)(outp + 4 * tid + 2 * plane) = o2;
}

__global__ __launch_bounds__(256) void bgrid_row4(const float* __restrict__ img,
                                                  const float* __restrict__ grid,
                                                  float* __restrict__ out)
{
    const int yb = blockIdx.x * 4;          // rows yb..yb+3
    const int b = blockIdx.y;
    const int tid = threadIdx.x;

    __shared__ __align__(16) uint H[4][HSZ];   // 25 KB

    const size_t plane = (size_t)HH * WW;
    const size_t rbase = (size_t)b * 3 * plane + (size_t)yb * WW;
    const float* ip = img + rbase + 4 * tid;

    // ---- prefetch rows 0,1 at entry (in flight during staging) ----
    const f4 rA = ld4(ip);
    const f4 gA = ld4(ip + plane);
    const f4 bA = ld4(ip + 2 * plane);
    const f4 rB = ld4(ip + WW);
    const f4 gB = ld4(ip + WW + plane);
    const f4 bB = ld4(ip + WW + 2 * plane);

    // ---- per-row y constants (block-uniform scalars) ----
    float uyv[4]; int y0v[4]; int y1v[4];
#pragma unroll
    for (int r = 0; r < 4; r++) {
        float uy = fminf((yb + r) * (15.0f / 1023.0f), 15.0f);
        uyv[r] = uy;
        y0v[r] = (int)uy;
        y1v[r] = min(y0v[r] + 1, GH - 1);
    }
    const bool same_cell = (y0v[0] == y0v[3]);

    // ---- stage y-lerped, z-dup'd f16 slabs for 4 rows ----
    const float* gbase = grid + (size_t)b * (NC * GD * GH * GW); // [c][z][y][x]
#pragma unroll
    for (int j = 0; j < 6; j++) {
        int t = tid + 256 * j;          // 0..1535 = 8x * 16z * 12c
        int x = t & 7;
        int z = (t >> 3) & 15;
        int c = t >> 7;
        int zp = min(z + 1, GD - 1);
        const float* bc = gbase + c * (GD * GH * GW) + x;
        int off = x * XSD + z * ZSD + c;
        if (same_cell) {
            const int ya0 = y0v[0], ya1 = y1v[0];
            float a0 = bc[(z  * GH + ya0) * GW];
            float a1 = bc[(z  * GH + ya1) * GW];
            float e0 = bc[(zp * GH + ya0) * GW];
            float e1 = bc[(zp * GH + ya1) * GW];
            float d0 = a1 - a0, d1 = e1 - e0;
#pragma unroll
            for (int r = 0; r < 4; r++) {
                float w = uyv[r] - (float)ya0;
                HU pk;
                pk.h = h2{(_Float16)fmaf(w, d0, a0), (_Float16)fmaf(w, d1, e0)};
                H[r][off] = pk.u;
            }
        } else {
#pragma unroll
            for (int r = 0; r < 4; r++) {
                const int yy0 = y0v[r], yy1 = y1v[r];
                float a0 = bc[(z  * GH + yy0) * GW];
                float a1 = bc[(z  * GH + yy1) * GW];
                float e0 = bc[(zp * GH + yy0) * GW];
                float e1 = bc[(zp * GH + yy1) * GW];
                float w = uyv[r] - (float)yy0;
                HU pk;
                pk.h = h2{(_Float16)fmaf(w, a1 - a0, a0), (_Float16)fmaf(w, e1 - e0, e0)};
                H[r][off] = pk.u;
            }
        }
    }

    // ---- prefetch rows 2,3 (latency covered by rows 0-1 compute) ----
    const f4 rC = ld4(ip + 2 * WW);
    const f4 gC = ld4(ip + 2 * WW + plane);
    const f4 bC = ld4(ip + 2 * WW + 2 * plane);
    const f4 rD = ld4(ip + 3 * WW);
    const f4 gD = ld4(ip + 3 * WW + plane);
    const f4 bD = ld4(ip + 3 * WW + 2 * plane);

    __syncthreads();

    run4(H[0], rA, gA, bA, out + rbase,          tid, plane);
    run4(H[1], rB, gB, bB, out + rbase + WW,     tid, plane);
    run4(H[2], rC, gC, bC, out + rbase + 2 * WW, tid, plane);
    run4(H[3], rD, gD, bD, out + rbase + 3 * WW, tid, plane);
}

extern "C" void kernel_launch(void* const* d_in, const int* in_sizes, int n_in,
                              void* d_out, int out_size, void* d_ws, size_t ws_size,
                              hipStream_t stream) {
    const float* grid  = (const float*)d_in[0];
    const float* image = (const float*)d_in[1];
    float* out = (float*)d_out;

    dim3 blk(256);
    dim3 grd(HH / 4, BB);   // one block per (4 rows, batch)
    bgrid_row4<<<grd, blk, 0, stream>>>(image, grid, out);
}

// Round 9
// 24.838 us; speedup vs baseline: 1.1528x; 1.0924x over previous
//
#include <hip/hip_runtime.h>

// Problem constants (match reference setup_inputs)
#define BB 4
#define HH 1024
#define WW 1024
#define NC 12
#define GD 16
#define GH 16
#define GW 8

// LDS slab F[x][z][c]: z-stride padded to 52 floats (208 B) so that the
// quad-bank group (addr/16 mod 8) = (5*z + q) mod 8 -> 16 random z values
// spread over 8 groups (<=2-way conflict, ~free). x-stride 832 floats.
// Empirically the best structure of the session (24.2 us): 1 row/block,
// 4 px/thread, f32 slab. f16 z-dup (6 ds_read/px), 2-row, 4-row, nt
// streams, and split prefetch all measured equal or worse (24.8-28.6).
#define ZS 52
#define XS (GD * ZS)          // 832
#define FSZ (GW * XS)         // 6656 floats = 26624 B

__global__ __launch_bounds__(256) void bgrid_row(const float* __restrict__ img,
                                                 const float* __restrict__ grid,
                                                 float* __restrict__ out)
{
    const int y = blockIdx.x;
    const int b = blockIdx.y;
    const int tid = threadIdx.x;

    __shared__ __align__(16) float F[FSZ];

    // ---- per-row y interpolation constants (block-uniform) ----
    float uy = fminf(fmaxf(y * (15.0f / 1023.0f), 0.0f), 15.0f);
    int y0 = (int)uy;
    int y1 = min(y0 + 1, GH - 1);
    float wy = uy - (float)y0;

    // ---- stage y-lerped grid slab into LDS: F[x][z][c] ----
    const float* gb = grid + (size_t)b * (NC * GD * GH * GW); // [c][z][y][x]
#pragma unroll
    for (int j = 0; j < 6; j++) {
        int t = tid + 256 * j;          // t in [0, 1536)
        int x = t & 7;
        int z = (t >> 3) & 15;
        int c = t >> 7;                 // 0..11
        int gi = (c * GD + z) * (GH * GW) + x;
        float g0 = gb[gi + y0 * GW];
        float g1 = gb[gi + y1 * GW];
        F[x * XS + z * ZS + c] = g0 + wy * (g1 - g0);
    }
    __syncthreads();

    // ---- process 4 pixels per thread with float4 I/O ----
    const size_t plane = (size_t)HH * WW;
    const size_t rowoff = (size_t)b * 3 * plane + (size_t)y * WW;
    const float4 r4 = *(const float4*)(img + rowoff + 4 * tid);
    const float4 g4 = *(const float4*)(img + rowoff + plane + 4 * tid);
    const float4 b4 = *(const float4*)(img + rowoff + 2 * plane + 4 * tid);

    float4 o0, o1, o2;
    float* o0p = (float*)&o0; float* o1p = (float*)&o1; float* o2p = (float*)&o2;
    const float* rp = (const float*)&r4;
    const float* gp = (const float*)&g4;
    const float* bp = (const float*)&b4;

#pragma unroll
    for (int p = 0; p < 4; p++) {
        const int px = 4 * tid + p;
        const float r = rp[p], g = gp[p], bl = bp[p];

        float ux = fminf(px * (7.0f / 1023.0f), 7.0f);
        int x0 = (int)ux;
        int x1 = min(x0 + 1, GW - 1);
        float wx = ux - (float)x0;

        float lum = 0.299f * r + 0.587f * g + 0.114f * bl;
        float uz = fminf(fmaxf(lum * 15.0f, 0.0f), 15.0f);
        int z0 = (int)uz;
        int z1 = min(z0 + 1, GD - 1);
        float wz = uz - (float)z0;

        const float* f00 = &F[x0 * XS + z0 * ZS];  // (x0,z0)
        const float* f10 = &F[x1 * XS + z0 * ZS];  // (x1,z0)
        const float* f01 = &F[x0 * XS + z1 * ZS];  // (x0,z1)
        const float* f11 = &F[x1 * XS + z1 * ZS];  // (x1,z1)

        float cf[12];
#pragma unroll
        for (int q = 0; q < 3; q++) {
            const float4 a = *(const float4*)(f00 + 4 * q);
            const float4 bq = *(const float4*)(f10 + 4 * q);
            const float4 c = *(const float4*)(f01 + 4 * q);
            const float4 d = *(const float4*)(f11 + 4 * q);
            // lerp in x, then z
            float m0x = a.x + wx * (bq.x - a.x), m1x = c.x + wx * (d.x - c.x);
            float m0y = a.y + wx * (bq.y - a.y), m1y = c.y + wx * (d.y - c.y);
            float m0z = a.z + wx * (bq.z - a.z), m1z = c.z + wx * (d.z - c.z);
            float m0w = a.w + wx * (bq.w - a.w), m1w = c.w + wx * (d.w - c.w);
            cf[4 * q + 0] = m0x + wz * (m1x - m0x);
            cf[4 * q + 1] = m0y + wz * (m1y - m0y);
            cf[4 * q + 2] = m0z + wz * (m1z - m0z);
            cf[4 * q + 3] = m0w + wz * (m1w - m0w);
        }

        float v0 = cf[0] * r + cf[1] * g + cf[2] * bl + cf[9];
        float v1 = cf[3] * r + cf[4] * g + cf[5] * bl + cf[10];
        float v2 = cf[6] * r + cf[7] * g + cf[8] * bl + cf[11];
        o0p[p] = fminf(fmaxf(v0, 0.0f), 1.0f);
        o1p[p] = fminf(fmaxf(v1, 0.0f), 1.0f);
        o2p[p] = fminf(fmaxf(v2, 0.0f), 1.0f);
    }

    *(float4*)(out + rowoff + 4 * tid) = o0;
    *(float4*)(out + rowoff + plane + 4 * tid) = o1;
    *(float4*)(out + rowoff + 2 * plane + 4 * tid) = o2;
}

extern "C" void kernel_launch(void* const* d_in, const int* in_sizes, int n_in,
                              void* d_out, int out_size, void* d_ws, size_t ws_size,
                              hipStream_t stream) {
    const float* grid  = (const float*)d_in[0];
    const float* image = (const float*)d_in[1];
    float* out = (float*)d_out;

    dim3 blk(256);
    dim3 grd(HH, BB);   // one block per (row, batch)
    bgrid_row<<<grd, blk, 0, stream>>>(image, grid, out);
}